// Round 7
// baseline (310.508 us; speedup 1.0000x reference)
//
#include <hip/hip_runtime.h>

#define NTOK 32768

typedef __attribute__((ext_vector_type(8))) short short8;
typedef __attribute__((ext_vector_type(4))) short short4_t;
typedef __attribute__((ext_vector_type(4))) float f32x4;

__device__ __forceinline__ short f2b(float f) {
    union { float f; unsigned u; } v; v.f = f;
    unsigned r = v.u + 0x7fffu + ((v.u >> 16) & 1u);
    return (short)(r >> 16);
}
__device__ __forceinline__ float b2f(short s) {
    union { float f; unsigned u; } v;
    v.u = ((unsigned)(unsigned short)s) << 16;
    return v.f;
}

// ------- setup: repack conv weights, bf16 conversions, init accumulators -------
__global__ void k_repack(const float* __restrict__ w1, const float* __restrict__ w2,
                         const float* __restrict__ w8, const float* __restrict__ wef,
                         const float* __restrict__ wq, const float* __restrict__ bEF,
                         short* __restrict__ wb1, short* __restrict__ wb2,
                         short* __restrict__ wb8, short* __restrict__ wefb,
                         short* __restrict__ wqb, float* __restrict__ kp,
                         float* __restrict__ vp, float* __restrict__ qd)
{
    int i = blockIdx.x * 256 + threadIdx.x;
    if (i >= 2349312) return;
    if (i >= 2347008) { qd[i - 2347008] = 0.f; return; }
    if (i >= 2338816) {
        int j = i - 2338816;
        float v = bEF[j & 63];
        kp[j] = v; vp[j] = v; return;
    }
    if (i >= 2322432) { int j = i - 2322432; wqb[j] = f2b(wq[j]); return; }
    if (i >= 225280)  { int j = i - 225280;  wefb[j] = f2b(wef[j]); return; }
    if (i >= 221184)  { int j = i - 221184;  wb8[j] = f2b(w8[j]); return; }
    int sel = i >= 110592;
    int j = sel ? i - 110592 : i;
    int tap = j >> 12;
    int r = j & 4095;
    int oc = r >> 6, ic = r & 63;
    const float* w = sel ? w2 : w1;
    short* o = sel ? wb2 : wb1;
    o[j] = f2b(w[(oc * 64 + ic) * 27 + tap]);
}

// ---------------- fused LayerNorm + QKVV GEMM (MFMA), bf16 W ----------------
// qkvvb layout: bf16 [isel(4)][b(2)][h(4)][d(16)][N]  (512 rows x 32768 = 32 MB)
__global__ __launch_bounds__(256) void k_ln_qkvv(
    const float* __restrict__ x, const float* __restrict__ lnw,
    const float* __restrict__ lnb, const short* __restrict__ wqb,
    short* __restrict__ qkvvb)
{
    __shared__ __align__(16) short Wl[256 * 72];
    __shared__ __align__(16) short tr[256 * 72];
    __shared__ float red1[4][64], red2[4][64];
    __shared__ float mu_s[64], rs_s[64];
    short* al = tr;                                 // bf16 [64 t][72]

    int bid = blockIdx.x;
    int b = bid >> 9;
    int n0 = (bid & 511) << 6;
    int tid = threadIdx.x;

    for (int i = tid; i < 2048; i += 256) {
        int out = i >> 3, q8 = (i & 7) * 8;
        *(short8*)&Wl[out * 72 + q8] = *(const short8*)&wqb[out * 64 + q8];
    }

    int t = tid & 63, cq = tid >> 6;
    float xr[16];
    float s1 = 0.f, s2 = 0.f;
    const float* xb = x + (((size_t)(b * 64 + cq * 16)) << 15) + n0 + t;
#pragma unroll
    for (int j = 0; j < 16; ++j) {
        float v = xb[(size_t)j << 15];
        xr[j] = v; s1 += v; s2 += v * v;
    }
    red1[cq][t] = s1; red2[cq][t] = s2;
    __syncthreads();
    if (tid < 64) {
        float a = red1[0][tid] + red1[1][tid] + red1[2][tid] + red1[3][tid];
        float q = red2[0][tid] + red2[1][tid] + red2[2][tid] + red2[3][tid];
        float mu = a * (1.f / 64.f);
        float var = q * (1.f / 64.f) - mu * mu;
        mu_s[tid] = mu;
        rs_s[tid] = rsqrtf(var + 1e-5f);
    }
    __syncthreads();
    {
        float mu = mu_s[t], rs = rs_s[t];
        short8 p0, p1;
#pragma unroll
        for (int j = 0; j < 8; ++j) {
            int c = cq * 16 + j;
            p0[j] = f2b((xr[j] - mu) * rs * lnw[c] + lnb[c]);
        }
#pragma unroll
        for (int j = 0; j < 8; ++j) {
            int c = cq * 16 + 8 + j;
            p1[j] = f2b((xr[8 + j] - mu) * rs * lnw[c] + lnb[c]);
        }
        *(short8*)&al[t * 72 + cq * 16] = p0;
        *(short8*)&al[t * 72 + cq * 16 + 8] = p1;
    }
    __syncthreads();

    int w = tid >> 6, lane = tid & 63, l15 = lane & 15, quad = lane >> 4;
    f32x4 acc[4][4];
#pragma unroll
    for (int mt = 0; mt < 4; ++mt)
#pragma unroll
        for (int nt = 0; nt < 4; ++nt) acc[mt][nt] = (f32x4){0.f, 0.f, 0.f, 0.f};
#pragma unroll
    for (int ks = 0; ks < 2; ++ks) {
        short8 af[4], bf[4];
#pragma unroll
        for (int mt = 0; mt < 4; ++mt)
            af[mt] = *(const short8*)&al[(mt * 16 + l15) * 72 + quad * 8 + ks * 32];
#pragma unroll
        for (int nt = 0; nt < 4; ++nt)
            bf[nt] = *(const short8*)&Wl[(w * 64 + nt * 16 + l15) * 72 + quad * 8 + ks * 32];
#pragma unroll
        for (int mt = 0; mt < 4; ++mt)
#pragma unroll
            for (int nt = 0; nt < 4; ++nt)
                acc[mt][nt] = __builtin_amdgcn_mfma_f32_16x16x32_bf16(af[mt], bf[nt], acc[mt][nt], 0, 0, 0);
    }
    __syncthreads();

#pragma unroll
    for (int mt = 0; mt < 4; ++mt)
#pragma unroll
        for (int nt = 0; nt < 4; ++nt) {
            int out = w * 64 + nt * 16 + l15;
            short4_t sv;
#pragma unroll
            for (int r = 0; r < 4; ++r) sv[r] = f2b(acc[mt][nt][r]);
            *(short4_t*)&tr[out * 72 + mt * 16 + quad * 4] = sv;
        }
    __syncthreads();
    for (int i = tid; i < 2048; i += 256) {
        int o = i >> 3, tq = (i & 7) * 8;
        short8 v = *(const short8*)&tr[o * 72 + tq];
        int isel = o >> 6, h = (o >> 4) & 3, d = o & 15;
        *(short8*)&qkvvb[((size_t)(((isel * 2 + b) * 4 + h) * 16 + d) << 15) + n0 + tq] = v;
    }
}

// ------- merged MFMA: k/v projections + q.k logits + L2-norm accumulators -------
__global__ __launch_bounds__(256) void k_pq(
    const short* __restrict__ qkvvb, const short* __restrict__ wefb,
    float* __restrict__ kp, float* __restrict__ vp, float* __restrict__ qd,
    float* __restrict__ qn_acc, float* __restrict__ kn_acc)
{
    __shared__ float redb[3][64][38];
    int kc = blockIdx.x, bh = blockIdx.y;
    int tid = threadIdx.x;
    int w = tid >> 6, lane = tid & 63, l15 = lane & 15, quad = lane >> 4;
    size_t qrow = ((size_t)(bh * 16 + l15)) << 15;
    size_t krow = ((size_t)(128 + bh * 16 + l15)) << 15;
    size_t vrow = ((size_t)(384 + bh * 16 + l15)) << 15;
    int nbase = kc * 1024 + w * 256 + quad * 8;
    f32x4 acck[4], accv[4], accqd, accqq, acckk;
#pragma unroll
    for (int nt = 0; nt < 4; ++nt) {
        acck[nt] = (f32x4){0.f, 0.f, 0.f, 0.f};
        accv[nt] = (f32x4){0.f, 0.f, 0.f, 0.f};
    }
    accqd = (f32x4){0.f, 0.f, 0.f, 0.f};
    accqq = (f32x4){0.f, 0.f, 0.f, 0.f};
    acckk = (f32x4){0.f, 0.f, 0.f, 0.f};
#pragma unroll
    for (int ks = 0; ks < 8; ++ks) {
        int n = nbase + ks * 32;
        short8 qf = *(const short8*)&qkvvb[qrow + n];
        short8 kf = *(const short8*)&qkvvb[krow + n];
        short8 vf = *(const short8*)&qkvvb[vrow + n];
        accqd = __builtin_amdgcn_mfma_f32_16x16x32_bf16(qf, kf, accqd, 0, 0, 0);
        accqq = __builtin_amdgcn_mfma_f32_16x16x32_bf16(qf, qf, accqq, 0, 0, 0);
        acckk = __builtin_amdgcn_mfma_f32_16x16x32_bf16(kf, kf, acckk, 0, 0, 0);
#pragma unroll
        for (int nt = 0; nt < 4; ++nt) {
            short8 wf = *(const short8*)&wefb[(((size_t)(nt * 16 + l15)) << 15) + n];
            acck[nt] = __builtin_amdgcn_mfma_f32_16x16x32_bf16(kf, wf, acck[nt], 0, 0, 0);
            accv[nt] = __builtin_amdgcn_mfma_f32_16x16x32_bf16(vf, wf, accv[nt], 0, 0, 0);
        }
    }
    int diag = (quad == (l15 >> 2));
    float qqv = diag ? accqq[l15 & 3] : 0.f;
    float kkv = diag ? acckk[l15 & 3] : 0.f;
    if (w > 0) {
        float* p = &redb[w - 1][lane][0];
#pragma unroll
        for (int nt = 0; nt < 4; ++nt)
#pragma unroll
            for (int r = 0; r < 4; ++r) { p[nt * 4 + r] = acck[nt][r]; p[16 + nt * 4 + r] = accv[nt][r]; }
#pragma unroll
        for (int r = 0; r < 4; ++r) p[32 + r] = accqd[r];
        p[36] = qqv; p[37] = kkv;
    }
    __syncthreads();
    if (w == 0) {
#pragma unroll
        for (int wv = 0; wv < 3; ++wv) {
            const float* p = &redb[wv][lane][0];
#pragma unroll
            for (int nt = 0; nt < 4; ++nt)
#pragma unroll
                for (int r = 0; r < 4; ++r) { acck[nt][r] += p[nt * 4 + r]; accv[nt][r] += p[16 + nt * 4 + r]; }
#pragma unroll
            for (int r = 0; r < 4; ++r) accqd[r] += p[32 + r];
            qqv += p[36]; kkv += p[37];
        }
        int d = quad * 4;
#pragma unroll
        for (int nt = 0; nt < 4; ++nt)
#pragma unroll
            for (int r = 0; r < 4; ++r) {
                int idx = (bh * 16 + d + r) * 64 + nt * 16 + l15;
                atomicAdd(&kp[idx], acck[nt][r]);
                atomicAdd(&vp[idx], accv[nt][r]);
            }
#pragma unroll
        for (int r = 0; r < 4; ++r)
            atomicAdd(&qd[bh * 256 + (d + r) * 16 + l15], accqd[r]);
        if (diag) {
            atomicAdd(&qn_acc[bh * 16 + l15], qqv);
            atomicAdd(&kn_acc[bh * 16 + l15], kkv);
        }
    }
}

// ---------------- norm finalize + channel-attention softmax ----------------
__global__ void k_softmax_ca(const float* __restrict__ qd,
    const float* __restrict__ qn_acc, const float* __restrict__ kn_acc,
    const float* __restrict__ temp1, float* __restrict__ attn,
    float* __restrict__ iqn, float* __restrict__ ikn)
{
    __shared__ float iqs[128], iks[128];
    int tid = threadIdx.x;
    if (tid < 128) {
        float v = 1.f / fmaxf(sqrtf(qn_acc[tid]), 1e-12f);
        iqs[tid] = v; iqn[tid] = v;
    } else {
        int j = tid - 128;
        float v = 1.f / fmaxf(sqrtf(kn_acc[j]), 1e-12f);
        iks[j] = v; ikn[j] = v;
    }
    __syncthreads();
    int r = tid;
    if (r >= 128) return;
    int bh = r >> 4;
    int h = bh & 3;
    float iq = iqs[r];
    float t1 = temp1[h];
    float sc[16];
    float mx = -1e30f;
#pragma unroll
    for (int e = 0; e < 16; ++e) {
        float v = qd[r * 16 + e] * iq * iks[bh * 16 + e] * t1;
        sc[e] = v; mx = fmaxf(mx, v);
    }
    float s = 0.f;
#pragma unroll
    for (int e = 0; e < 16; ++e) { sc[e] = __expf(sc[e] - mx); s += sc[e]; }
    float inv = 1.f / s;
#pragma unroll
    for (int e = 0; e < 16; ++e) attn[r * 16 + e] = sc[e] * inv;
}

// ---------------- fused x_ca + spatial attention; bf16 outputs ----------------
__global__ __launch_bounds__(256) void k_attn(
    const short* __restrict__ qkvvb, const float* __restrict__ inv_qn,
    const float* __restrict__ kp, const float* __restrict__ vp,
    const float* __restrict__ temp2, const float* __restrict__ a_ca,
    short* __restrict__ xsab, short* __restrict__ xcab)
{
    __shared__ float kl[16][64];
    __shared__ float vl[16][64];
    __shared__ float alca[16][16];
    __shared__ float iq[16];
    int bh = blockIdx.y; int b = bh >> 2, h = bh & 3;
    int tid = threadIdx.x;
    for (int i = tid; i < 1024; i += 256) {
        kl[i >> 6][i & 63] = kp[bh * 1024 + i];
        vl[i >> 6][i & 63] = vp[bh * 1024 + i];
    }
    alca[tid >> 4][tid & 15] = a_ca[bh * 256 + tid];
    if (tid < 16) iq[tid] = inv_qn[bh * 16 + tid];
    __syncthreads();
    int n = blockIdx.x * 256 + tid;

    {
        const short* vbase = qkvvb + (((size_t)(256 + bh * 16)) << 15) + n;
        float acc[16];
#pragma unroll
        for (int d = 0; d < 16; ++d) acc[d] = 0.f;
#pragma unroll
        for (int e = 0; e < 16; ++e) {
            float va = b2f(vbase[(size_t)e << 15]);
#pragma unroll
            for (int d = 0; d < 16; ++d) acc[d] += alca[d][e] * va;
        }
        short8 lo, hi;
#pragma unroll
        for (int j = 0; j < 8; ++j) { lo[j] = f2b(acc[j]); hi[j] = f2b(acc[j + 8]); }
        short* op = xcab + ((size_t)(b * NTOK + n)) * 64 + h * 16;
        *(short8*)&op[0] = lo;
        *(short8*)&op[8] = hi;
    }

    const short* qbase = qkvvb + (((size_t)(bh * 16)) << 15) + n;
    float qn_[16];
#pragma unroll
    for (int d = 0; d < 16; ++d) qn_[d] = b2f(qbase[(size_t)d << 15]) * iq[d];
    float t2 = temp2[h];
    float sc[64];
#pragma unroll
    for (int p = 0; p < 64; ++p) sc[p] = 0.f;
#pragma unroll
    for (int d = 0; d < 16; ++d) {
        float qv = qn_[d];
        const float4* kr = (const float4*)&kl[d][0];
#pragma unroll
        for (int p4 = 0; p4 < 16; ++p4) {
            float4 kv = kr[p4];
            sc[p4 * 4 + 0] += qv * kv.x; sc[p4 * 4 + 1] += qv * kv.y;
            sc[p4 * 4 + 2] += qv * kv.z; sc[p4 * 4 + 3] += qv * kv.w;
        }
    }
    float mx = -1e30f;
#pragma unroll
    for (int p = 0; p < 64; ++p) { sc[p] *= t2; mx = fmaxf(mx, sc[p]); }
    float s = 0.f;
#pragma unroll
    for (int p = 0; p < 64; ++p) { sc[p] = __expf(sc[p] - mx); s += sc[p]; }
    float inv = 1.f / s;
#pragma unroll
    for (int p = 0; p < 64; ++p) sc[p] *= inv;
    short* ob = xsab + (size_t)b * 2097152 + n;
#pragma unroll
    for (int d = 0; d < 16; ++d) {
        const float4* vr = (const float4*)&vl[d][0];
        float a0 = 0, a1 = 0, a2 = 0, a3 = 0;
#pragma unroll
        for (int p4 = 0; p4 < 16; ++p4) {
            float4 vv = vr[p4];
            a0 += sc[p4 * 4] * vv.x; a1 += sc[p4 * 4 + 1] * vv.y;
            a2 += sc[p4 * 4 + 2] * vv.z; a3 += sc[p4 * 4 + 3] * vv.w;
        }
        ob[(size_t)(d * 4 + h) << 15] = f2b((a0 + a1) + (a2 + a3));
    }
}

// ---------------- EPA epilogue (bf16 xsa/xca inputs) ----------------
__global__ __launch_bounds__(256) void k_epilogue(
    const float* __restrict__ x, const short* __restrict__ xsab,
    const short* __restrict__ xcab, const float* __restrict__ Wo1,
    const float* __restrict__ bo1, const float* __restrict__ Wo2,
    const float* __restrict__ bo2, const float* __restrict__ gamma,
    float* __restrict__ attn_skip, short* __restrict__ gA)
{
    __shared__ float W1[32][64];
    __shared__ float W2[32][64];
    int tid = threadIdx.x;
    for (int i = tid; i < 2048; i += 256) {
        W1[i >> 6][i & 63] = Wo1[i];
        W2[i >> 6][i & 63] = Wo2[i];
    }
    __syncthreads();
    int bid = blockIdx.x;
    int b = bid >> 9;
    int n0 = (bid & 511) << 6;
    int t = tid & 63, cg = tid >> 6;
    int n = n0 + t;
    const short* row = (cg < 2) ? xsab + (size_t)b * 2097152 + (size_t)n * 64
                                : xcab + ((size_t)(b * NTOK + n)) * 64;
    const float* Wb = (cg < 2) ? &W1[(cg & 1) * 16][0] : &W2[(cg & 1) * 16][0];
    const float* bias = (cg < 2) ? bo1 + (cg & 1) * 16 : bo2 + (cg & 1) * 16;
    float acc[16];
#pragma unroll
    for (int j = 0; j < 16; ++j) acc[j] = 0.f;
#pragma unroll
    for (int c8 = 0; c8 < 8; ++c8) {
        short8 rv8 = *(const short8*)&row[c8 * 8];
        float rv[8];
#pragma unroll
        for (int q = 0; q < 8; ++q) rv[q] = b2f(rv8[q]);
#pragma unroll
        for (int j = 0; j < 16; ++j) {
            const float* wr = &Wb[j * 64 + c8 * 8];
#pragma unroll
            for (int q = 0; q < 8; ++q) acc[j] += rv[q] * wr[q];
        }
    }
    float vals[16];
#pragma unroll
    for (int j = 0; j < 16; ++j) {
        int c = cg * 16 + j;
        size_t idx = (((size_t)(b * 64 + c)) << 15) + n;
        float v = x[idx] + gamma[c] * (acc[j] + bias[j]);
        attn_skip[idx] = v;
        vals[j] = v;
    }
    short8 lo, hi;
#pragma unroll
    for (int j = 0; j < 8; ++j) { lo[j] = f2b(vals[j]); hi[j] = f2b(vals[j + 8]); }
    short* gp = gA + ((size_t)(b * NTOK + n)) * 64 + cg * 16;
    *(short8*)&gp[0] = lo;
    *(short8*)&gp[8] = hi;
}

// ---------------- MFMA implicit-GEMM 3x3x3 conv; weights from global ----------------
template <int MODE>
__global__ __launch_bounds__(256) void k_conv3m(
    const short* __restrict__ gin, const short* __restrict__ wb,
    const float* __restrict__ bnw, const float* __restrict__ bnb,
    const float* __restrict__ skip, short* __restrict__ goutS,
    const short* __restrict__ wb8, const float* __restrict__ b8,
    float* __restrict__ io)
{
    __shared__ __align__(16) short inl_s[24480];   // [3z][6y][34x][40 icpad]
    __shared__ __align__(16) short w8l[MODE ? 5120 : 16];
    __shared__ __align__(16) short a2_s[MODE ? 9216 : 16];
    int bx = blockIdx.x;
    int bb = bx >> 8;
    int z0 = (bx >> 3) & 31;
    int y0 = (bx & 7) * 4;
    int tid = threadIdx.x;
    int lane = tid & 63, wv = tid >> 6;
    int l15 = lane & 15, quad = lane >> 4;

    f32x4 acc[2][4];
#pragma unroll
    for (int s = 0; s < 2; ++s)
#pragma unroll
        for (int nt = 0; nt < 4; ++nt) acc[s][nt] = (f32x4){0.f, 0.f, 0.f, 0.f};

    if (MODE == 1) {
        // w8l: [128 rows = oc*2+ks][40 pad], row holds wb8[oc*64 + ks*32 + 0..31]
        for (int i = tid; i < 512; i += 256) {
            int ocw = i >> 2, cq = (i & 3) * 8;
            *(short8*)&w8l[ocw * 40 + cq] = *(const short8*)&wb8[(ocw >> 1) * 64 + (ocw & 1) * 32 + cq];
        }
    }

    for (int chunk = 0; chunk < 2; ++chunk) {
        __syncthreads();
        for (int i = tid; i < 2448; i += 256) {
            int p = i >> 2, icq = i & 3;
            int xi = p % 34; int t2 = p / 34; int yi = t2 % 6; int zi = t2 / 6;
            int gz = z0 + zi - 1, gy = y0 + yi - 1, gx = xi - 1;
            short8 v = {0, 0, 0, 0, 0, 0, 0, 0};
            if ((unsigned)gz < 32u && (unsigned)gy < 32u && (unsigned)gx < 32u)
                v = *(const short8*)&gin[((size_t)(bb * NTOK + gz * 1024 + gy * 32 + gx)) * 64 + chunk * 32 + icq * 8];
            *(short8*)&inl_s[p * 40 + icq * 8] = v;
        }
        __syncthreads();
        const short* wbc = wb + chunk * 32 + quad * 8 + l15 * 64;
#pragma unroll
        for (int kz = 0; kz < 3; ++kz)
#pragma unroll
            for (int ky = 0; ky < 3; ++ky) {
                int rowb = (kz * 6 + wv + ky) * 34;
#pragma unroll
                for (int kx = 0; kx < 3; ++kx) {
                    int tap = (kz * 3 + ky) * 3 + kx;
                    short8 bf[4];
#pragma unroll
                    for (int nt = 0; nt < 4; ++nt)
                        bf[nt] = *(const short8*)&wbc[(size_t)(tap * 64 + nt * 16) * 64];
#pragma unroll
                    for (int s = 0; s < 2; ++s) {
                        short8 af = *(const short8*)&inl_s[(rowb + s * 16 + l15 + kx) * 40 + quad * 8];
#pragma unroll
                        for (int nt = 0; nt < 4; ++nt)
                            acc[s][nt] = __builtin_amdgcn_mfma_f32_16x16x32_bf16(af, bf[nt], acc[s][nt], 0, 0, 0);
                    }
                }
            }
    }
    __syncthreads();
    float rb = rsqrtf(1.f + 1e-5f);
    if (MODE == 0) {
        short* outS = inl_s;
#pragma unroll
        for (int nt = 0; nt < 4; ++nt) {
            int oc = nt * 16 + l15;
            float sc_ = bnw[oc] * rb, sh_ = bnb[oc];
#pragma unroll
            for (int s = 0; s < 2; ++s) {
                f32x4 v = acc[s][nt];
#pragma unroll
                for (int r = 0; r < 4; ++r) {
                    int pos = wv * 32 + s * 16 + quad * 4 + r;
                    float val = v[r] * sc_ + sh_;
                    val = val >= 0.f ? val : 0.01f * val;
                    outS[pos * 72 + oc] = f2b(val);
                }
            }
        }
        __syncthreads();
        for (int i = tid; i < 1024; i += 256) {
            int p = i >> 3, cq = i & 7;
            short8 v = *(const short8*)&outS[p * 72 + cq * 8];
            int y = p >> 5, x = p & 31;
            *(short8*)&goutS[((size_t)(bb * NTOK + z0 * 1024 + (y0 + y) * 32 + x)) * 64 + cq * 8] = v;
        }
    } else {
        float* outF = (float*)inl_s;
#pragma unroll
        for (int nt = 0; nt < 4; ++nt) {
            int oc = nt * 16 + l15;
#pragma unroll
            for (int s = 0; s < 2; ++s) {
                f32x4 v = acc[s][nt];
#pragma unroll
                for (int r = 0; r < 4; ++r) {
                    int pos = wv * 32 + s * 16 + quad * 4 + r;
                    outF[oc * 132 + pos] = v[r];
                }
            }
        }
        __syncthreads();
        f32x4 skr[8];
#pragma unroll
        for (int it = 0; it < 8; ++it) {
            int i = it * 256 + tid;
            int oc = i >> 5, xq = i & 31, pos0 = xq * 4;
            f32x4 c4 = *(const f32x4*)&outF[oc * 132 + pos0];
            int y = pos0 >> 5, xx = pos0 & 31;
            size_t g = (((size_t)(bb * 64 + oc)) << 15) + ((z0 * 32 + (y0 + y)) * 32 + xx);
            f32x4 sk = *(const f32x4*)&skip[g];
            skr[it] = sk;
            float sc_ = bnw[oc] * rb, sh_ = bnb[oc];
#pragma unroll
            for (int r = 0; r < 4; ++r) {
                float val = c4[r] * sc_ + sh_ + sk[r];
                val = val >= 0.f ? val : 0.01f * val;
                a2_s[(pos0 + r) * 72 + oc] = f2b(val);
            }
        }
        __syncthreads();
        f32x4 acc2[2][4];
#pragma unroll
        for (int s = 0; s < 2; ++s)
#pragma unroll
            for (int nt = 0; nt < 4; ++nt) acc2[s][nt] = (f32x4){0.f, 0.f, 0.f, 0.f};
#pragma unroll
        for (int ks = 0; ks < 2; ++ks) {
            short8 a8[2], b8f[4];
#pragma unroll
            for (int s = 0; s < 2; ++s)
                a8[s] = *(const short8*)&a2_s[(wv * 32 + s * 16 + l15) * 72 + quad * 8 + ks * 32];
#pragma unroll
            for (int nt = 0; nt < 4; ++nt)
                b8f[nt] = *(const short8*)&w8l[((nt * 16 + l15) * 2 + ks) * 40 + quad * 8];
#pragma unroll
            for (int s = 0; s < 2; ++s)
#pragma unroll
                for (int nt = 0; nt < 4; ++nt)
                    acc2[s][nt] = __builtin_amdgcn_mfma_f32_16x16x32_bf16(a8[s], b8f[nt], acc2[s][nt], 0, 0, 0);
        }
        __syncthreads();
#pragma unroll
        for (int nt = 0; nt < 4; ++nt) {
            int oc = nt * 16 + l15;
#pragma unroll
            for (int s = 0; s < 2; ++s) {
                f32x4 v = acc2[s][nt];
#pragma unroll
                for (int r = 0; r < 4; ++r) {
                    int pos = wv * 32 + s * 16 + quad * 4 + r;
                    outF[oc * 132 + pos] = v[r];
                }
            }
        }
        __syncthreads();
#pragma unroll
        for (int it = 0; it < 8; ++it) {
            int i = it * 256 + tid;
            int oc = i >> 5, xq = i & 31, pos0 = xq * 4;
            f32x4 cv = *(const f32x4*)&outF[oc * 132 + pos0];
            int y = pos0 >> 5, xx = pos0 & 31;
            size_t g = (((size_t)(bb * 64 + oc)) << 15) + ((z0 * 32 + (y0 + y)) * 32 + xx);
            float bias8 = b8[oc];
            f32x4 o;
#pragma unroll
            for (int r = 0; r < 4; ++r) o[r] = skr[it][r] + cv[r] + bias8;
            *(f32x4*)&io[g] = o;
        }
    }
}

extern "C" void kernel_launch(void* const* d_in, const int* in_sizes, int n_in,
                              void* d_out, int out_size, void* d_ws, size_t ws_size,
                              hipStream_t stream) {
    const float* x      = (const float*)d_in[0];
    const float* ln_w   = (const float*)d_in[1];
    const float* ln_b   = (const float*)d_in[2];
    const float* gamma  = (const float*)d_in[3];
    const float* temp1  = (const float*)d_in[4];
    const float* temp2  = (const float*)d_in[5];
    const float* W_qkvv = (const float*)d_in[6];
    const float* W_EF   = (const float*)d_in[7];
    const float* b_EF   = (const float*)d_in[8];
    const float* W_o1   = (const float*)d_in[9];
    const float* b_o1   = (const float*)d_in[10];
    const float* W_o2   = (const float*)d_in[11];
    const float* b_o2   = (const float*)d_in[12];
    const float* conv1w = (const float*)d_in[13];
    const float* conv2w = (const float*)d_in[14];
    const float* bn1_w  = (const float*)d_in[15];
    const float* bn1_b  = (const float*)d_in[16];
    const float* bn2_w  = (const float*)d_in[17];
    const float* bn2_b  = (const float*)d_in[18];
    const float* conv8w = (const float*)d_in[19];
    const float* conv8b = (const float*)d_in[20];

    // WORKSPACE LAYOUT FIX: qkvvb is 512 rows x 32768 = 16,777,216 shorts (32 MB),
    // everything else must start AFTER it (round 5/6 overlapped -> bf16 NaN patterns).
    short* qkvvb = (short*)d_ws;                 // [0, 16777216) shorts
    float* kp    = (float*)(qkvvb + 16777216);   // 8192 floats
    float* vp    = kp + 8192;                    // 8192
    float* qd    = vp + 8192;                    // 2048
    float* qn_acc= qd + 2048;                    // 128
    float* kn_acc= qn_acc + 128;                 // 128
    float* a_ca  = kn_acc + 128;                 // 2048
    float* iqn   = a_ca + 2048;                  // 128
    float* ikn   = iqn + 128;                    // 128
    short* xcab  = (short*)(ikn + 128);          // 4194304 shorts
    short* xsab  = xcab + 4194304;               // 4194304
    short* gA    = xsab + 4194304;               // 4194304
    short* g1    = gA + 4194304;                 // 4194304
    short* wb1   = g1 + 4194304;                 // 110592
    short* wb2   = wb1 + 110592;                 // 110592
    short* wb8   = wb2 + 110592;                 // 4096
    short* wefb  = wb8 + 4096;                   // 2097152
    short* wqb   = wefb + 2097152;               // 16384

    float* attn_skip = (float*)d_out;

    hipLaunchKernelGGL(k_repack, dim3(9177), dim3(256), 0, stream,
                       conv1w, conv2w, conv8w, W_EF, W_qkvv, b_EF,
                       wb1, wb2, wb8, wefb, wqb, kp, vp, qd);
    hipLaunchKernelGGL(k_ln_qkvv, dim3(1024), dim3(256), 0, stream,
                       x, ln_w, ln_b, wqb, qkvvb);
    hipLaunchKernelGGL(k_pq, dim3(32, 8), dim3(256), 0, stream,
                       qkvvb, wefb, kp, vp, qd, qn_acc, kn_acc);
    hipLaunchKernelGGL(k_softmax_ca, dim3(1), dim3(256), 0, stream,
                       qd, qn_acc, kn_acc, temp1, a_ca, iqn, ikn);
    hipLaunchKernelGGL(k_attn, dim3(128, 8), dim3(256), 0, stream,
                       qkvvb, iqn, kp, vp, temp2, a_ca, xsab, xcab);
    hipLaunchKernelGGL(k_epilogue, dim3(1024), dim3(256), 0, stream,
                       x, xsab, xcab, W_o1, b_o1, W_o2, b_o2, gamma, attn_skip, gA);
    hipLaunchKernelGGL((k_conv3m<0>), dim3(512), dim3(256), 0, stream,
                       gA, wb1, bn1_w, bn1_b, (const float*)nullptr, g1,
                       (const short*)nullptr, (const float*)nullptr, (float*)nullptr);
    hipLaunchKernelGGL((k_conv3m<1>), dim3(512), dim3(256), 0, stream,
                       g1, wb2, bn2_w, bn2_b, attn_skip, (short*)nullptr,
                       wb8, conv8b, attn_skip);
}

// Round 8
// 256.576 us; speedup vs baseline: 1.2102x; 1.2102x over previous
//
#include <hip/hip_runtime.h>

#define NTOK 32768

typedef __attribute__((ext_vector_type(8))) short short8;
typedef __attribute__((ext_vector_type(4))) short short4_t;
typedef __attribute__((ext_vector_type(4))) float f32x4;

__device__ __forceinline__ short f2b(float f) {
    union { float f; unsigned u; } v; v.f = f;
    unsigned r = v.u + 0x7fffu + ((v.u >> 16) & 1u);
    return (short)(r >> 16);
}
__device__ __forceinline__ float b2f(short s) {
    union { float f; unsigned u; } v;
    v.u = ((unsigned)(unsigned short)s) << 16;
    return v.f;
}

// ------- setup: repack conv weights, bf16 conversions, init accumulators -------
__global__ void k_repack(const float* __restrict__ w1, const float* __restrict__ w2,
                         const float* __restrict__ w8, const float* __restrict__ wef,
                         const float* __restrict__ wq, const float* __restrict__ bEF,
                         short* __restrict__ wb1, short* __restrict__ wb2,
                         short* __restrict__ wb8, short* __restrict__ wefb,
                         short* __restrict__ wqb, float* __restrict__ kp,
                         float* __restrict__ vp, float* __restrict__ qd)
{
    int i = blockIdx.x * 256 + threadIdx.x;
    if (i >= 2349312) return;
    if (i >= 2347008) { qd[i - 2347008] = 0.f; return; }
    if (i >= 2338816) {
        int j = i - 2338816;
        float v = bEF[j & 63];
        kp[j] = v; vp[j] = v; return;
    }
    if (i >= 2322432) { int j = i - 2322432; wqb[j] = f2b(wq[j]); return; }
    if (i >= 225280)  { int j = i - 225280;  wefb[j] = f2b(wef[j]); return; }
    if (i >= 221184)  { int j = i - 221184;  wb8[j] = f2b(w8[j]); return; }
    int sel = i >= 110592;
    int j = sel ? i - 110592 : i;
    int tap = j >> 12;
    int r = j & 4095;
    int oc = r >> 6, ic = r & 63;
    const float* w = sel ? w2 : w1;
    short* o = sel ? wb2 : wb1;
    o[j] = f2b(w[(oc * 64 + ic) * 27 + tap]);
}

// ---------------- fused LayerNorm + QKVV GEMM (MFMA), bf16 W ----------------
// qkvvb layout: bf16 [isel(4)][b(2)][h(4)][d(16)][N]  (512 rows x 32768 = 32 MB)
__global__ __launch_bounds__(256) void k_ln_qkvv(
    const float* __restrict__ x, const float* __restrict__ lnw,
    const float* __restrict__ lnb, const short* __restrict__ wqb,
    short* __restrict__ qkvvb)
{
    __shared__ __align__(16) short Wl[256 * 72];
    __shared__ __align__(16) short tr[256 * 72];
    __shared__ float red1[4][64], red2[4][64];
    __shared__ float mu_s[64], rs_s[64];
    short* al = tr;                                 // bf16 [64 t][72]

    int bid = blockIdx.x;
    int b = bid >> 9;
    int n0 = (bid & 511) << 6;
    int tid = threadIdx.x;

    for (int i = tid; i < 2048; i += 256) {
        int out = i >> 3, q8 = (i & 7) * 8;
        *(short8*)&Wl[out * 72 + q8] = *(const short8*)&wqb[out * 64 + q8];
    }

    int t = tid & 63, cq = tid >> 6;
    float xr[16];
    float s1 = 0.f, s2 = 0.f;
    const float* xb = x + (((size_t)(b * 64 + cq * 16)) << 15) + n0 + t;
#pragma unroll
    for (int j = 0; j < 16; ++j) {
        float v = xb[(size_t)j << 15];
        xr[j] = v; s1 += v; s2 += v * v;
    }
    red1[cq][t] = s1; red2[cq][t] = s2;
    __syncthreads();
    if (tid < 64) {
        float a = red1[0][tid] + red1[1][tid] + red1[2][tid] + red1[3][tid];
        float q = red2[0][tid] + red2[1][tid] + red2[2][tid] + red2[3][tid];
        float mu = a * (1.f / 64.f);
        float var = q * (1.f / 64.f) - mu * mu;
        mu_s[tid] = mu;
        rs_s[tid] = rsqrtf(var + 1e-5f);
    }
    __syncthreads();
    {
        float mu = mu_s[t], rs = rs_s[t];
        short8 p0, p1;
#pragma unroll
        for (int j = 0; j < 8; ++j) {
            int c = cq * 16 + j;
            p0[j] = f2b((xr[j] - mu) * rs * lnw[c] + lnb[c]);
        }
#pragma unroll
        for (int j = 0; j < 8; ++j) {
            int c = cq * 16 + 8 + j;
            p1[j] = f2b((xr[8 + j] - mu) * rs * lnw[c] + lnb[c]);
        }
        *(short8*)&al[t * 72 + cq * 16] = p0;
        *(short8*)&al[t * 72 + cq * 16 + 8] = p1;
    }
    __syncthreads();

    int w = tid >> 6, lane = tid & 63, l15 = lane & 15, quad = lane >> 4;
    f32x4 acc[4][4];
#pragma unroll
    for (int mt = 0; mt < 4; ++mt)
#pragma unroll
        for (int nt = 0; nt < 4; ++nt) acc[mt][nt] = (f32x4){0.f, 0.f, 0.f, 0.f};
#pragma unroll
    for (int ks = 0; ks < 2; ++ks) {
        short8 af[4], bf[4];
#pragma unroll
        for (int mt = 0; mt < 4; ++mt)
            af[mt] = *(const short8*)&al[(mt * 16 + l15) * 72 + quad * 8 + ks * 32];
#pragma unroll
        for (int nt = 0; nt < 4; ++nt)
            bf[nt] = *(const short8*)&Wl[(w * 64 + nt * 16 + l15) * 72 + quad * 8 + ks * 32];
#pragma unroll
        for (int mt = 0; mt < 4; ++mt)
#pragma unroll
            for (int nt = 0; nt < 4; ++nt)
                acc[mt][nt] = __builtin_amdgcn_mfma_f32_16x16x32_bf16(af[mt], bf[nt], acc[mt][nt], 0, 0, 0);
    }
    __syncthreads();

#pragma unroll
    for (int mt = 0; mt < 4; ++mt)
#pragma unroll
        for (int nt = 0; nt < 4; ++nt) {
            int out = w * 64 + nt * 16 + l15;
            short4_t sv;
#pragma unroll
            for (int r = 0; r < 4; ++r) sv[r] = f2b(acc[mt][nt][r]);
            *(short4_t*)&tr[out * 72 + mt * 16 + quad * 4] = sv;
        }
    __syncthreads();
    for (int i = tid; i < 2048; i += 256) {
        int o = i >> 3, tq = (i & 7) * 8;
        short8 v = *(const short8*)&tr[o * 72 + tq];
        int isel = o >> 6, h = (o >> 4) & 3, d = o & 15;
        *(short8*)&qkvvb[((size_t)(((isel * 2 + b) * 4 + h) * 16 + d) << 15) + n0 + tq] = v;
    }
}

// ------- merged MFMA: k/v projections + q.k logits + L2-norm accumulators -------
__global__ __launch_bounds__(256) void k_pq(
    const short* __restrict__ qkvvb, const short* __restrict__ wefb,
    float* __restrict__ kp, float* __restrict__ vp, float* __restrict__ qd,
    float* __restrict__ qn_acc, float* __restrict__ kn_acc)
{
    __shared__ float redb[3][64][38];
    int kc = blockIdx.x, bh = blockIdx.y;
    int tid = threadIdx.x;
    int w = tid >> 6, lane = tid & 63, l15 = lane & 15, quad = lane >> 4;
    size_t qrow = ((size_t)(bh * 16 + l15)) << 15;
    size_t krow = ((size_t)(128 + bh * 16 + l15)) << 15;
    size_t vrow = ((size_t)(384 + bh * 16 + l15)) << 15;
    int nbase = kc * 1024 + w * 256 + quad * 8;
    f32x4 acck[4], accv[4], accqd, accqq, acckk;
#pragma unroll
    for (int nt = 0; nt < 4; ++nt) {
        acck[nt] = (f32x4){0.f, 0.f, 0.f, 0.f};
        accv[nt] = (f32x4){0.f, 0.f, 0.f, 0.f};
    }
    accqd = (f32x4){0.f, 0.f, 0.f, 0.f};
    accqq = (f32x4){0.f, 0.f, 0.f, 0.f};
    acckk = (f32x4){0.f, 0.f, 0.f, 0.f};
#pragma unroll
    for (int ks = 0; ks < 8; ++ks) {
        int n = nbase + ks * 32;
        short8 qf = *(const short8*)&qkvvb[qrow + n];
        short8 kf = *(const short8*)&qkvvb[krow + n];
        short8 vf = *(const short8*)&qkvvb[vrow + n];
        accqd = __builtin_amdgcn_mfma_f32_16x16x32_bf16(qf, kf, accqd, 0, 0, 0);
        accqq = __builtin_amdgcn_mfma_f32_16x16x32_bf16(qf, qf, accqq, 0, 0, 0);
        acckk = __builtin_amdgcn_mfma_f32_16x16x32_bf16(kf, kf, acckk, 0, 0, 0);
#pragma unroll
        for (int nt = 0; nt < 4; ++nt) {
            short8 wf = *(const short8*)&wefb[(((size_t)(nt * 16 + l15)) << 15) + n];
            acck[nt] = __builtin_amdgcn_mfma_f32_16x16x32_bf16(kf, wf, acck[nt], 0, 0, 0);
            accv[nt] = __builtin_amdgcn_mfma_f32_16x16x32_bf16(vf, wf, accv[nt], 0, 0, 0);
        }
    }
    int diag = (quad == (l15 >> 2));
    float qqv = diag ? accqq[l15 & 3] : 0.f;
    float kkv = diag ? acckk[l15 & 3] : 0.f;
    if (w > 0) {
        float* p = &redb[w - 1][lane][0];
#pragma unroll
        for (int nt = 0; nt < 4; ++nt)
#pragma unroll
            for (int r = 0; r < 4; ++r) { p[nt * 4 + r] = acck[nt][r]; p[16 + nt * 4 + r] = accv[nt][r]; }
#pragma unroll
        for (int r = 0; r < 4; ++r) p[32 + r] = accqd[r];
        p[36] = qqv; p[37] = kkv;
    }
    __syncthreads();
    if (w == 0) {
#pragma unroll
        for (int wv = 0; wv < 3; ++wv) {
            const float* p = &redb[wv][lane][0];
#pragma unroll
            for (int nt = 0; nt < 4; ++nt)
#pragma unroll
                for (int r = 0; r < 4; ++r) { acck[nt][r] += p[nt * 4 + r]; accv[nt][r] += p[16 + nt * 4 + r]; }
#pragma unroll
            for (int r = 0; r < 4; ++r) accqd[r] += p[32 + r];
            qqv += p[36]; kkv += p[37];
        }
        int d = quad * 4;
#pragma unroll
        for (int nt = 0; nt < 4; ++nt)
#pragma unroll
            for (int r = 0; r < 4; ++r) {
                int idx = (bh * 16 + d + r) * 64 + nt * 16 + l15;
                atomicAdd(&kp[idx], acck[nt][r]);
                atomicAdd(&vp[idx], accv[nt][r]);
            }
#pragma unroll
        for (int r = 0; r < 4; ++r)
            atomicAdd(&qd[bh * 256 + (d + r) * 16 + l15], accqd[r]);
        if (diag) {
            atomicAdd(&qn_acc[bh * 16 + l15], qqv);
            atomicAdd(&kn_acc[bh * 16 + l15], kkv);
        }
    }
}

// ---------------- norm finalize + channel-attention softmax ----------------
__global__ void k_softmax_ca(const float* __restrict__ qd,
    const float* __restrict__ qn_acc, const float* __restrict__ kn_acc,
    const float* __restrict__ temp1, float* __restrict__ attn,
    float* __restrict__ iqn, float* __restrict__ ikn)
{
    __shared__ float iqs[128], iks[128];
    int tid = threadIdx.x;
    if (tid < 128) {
        float v = 1.f / fmaxf(sqrtf(qn_acc[tid]), 1e-12f);
        iqs[tid] = v; iqn[tid] = v;
    } else {
        int j = tid - 128;
        float v = 1.f / fmaxf(sqrtf(kn_acc[j]), 1e-12f);
        iks[j] = v; ikn[j] = v;
    }
    __syncthreads();
    int r = tid;
    if (r >= 128) return;
    int bh = r >> 4;
    int h = bh & 3;
    float iq = iqs[r];
    float t1 = temp1[h];
    float sc[16];
    float mx = -1e30f;
#pragma unroll
    for (int e = 0; e < 16; ++e) {
        float v = qd[r * 16 + e] * iq * iks[bh * 16 + e] * t1;
        sc[e] = v; mx = fmaxf(mx, v);
    }
    float s = 0.f;
#pragma unroll
    for (int e = 0; e < 16; ++e) { sc[e] = __expf(sc[e] - mx); s += sc[e]; }
    float inv = 1.f / s;
#pragma unroll
    for (int e = 0; e < 16; ++e) attn[r * 16 + e] = sc[e] * inv;
}

// ---------------- fused x_ca + spatial attention; bf16 outputs ----------------
__global__ __launch_bounds__(256) void k_attn(
    const short* __restrict__ qkvvb, const float* __restrict__ inv_qn,
    const float* __restrict__ kp, const float* __restrict__ vp,
    const float* __restrict__ temp2, const float* __restrict__ a_ca,
    short* __restrict__ xsab, short* __restrict__ xcab)
{
    __shared__ float kl[16][64];
    __shared__ float vl[16][64];
    __shared__ float alca[16][16];
    __shared__ float iq[16];
    int bh = blockIdx.y; int b = bh >> 2, h = bh & 3;
    int tid = threadIdx.x;
    for (int i = tid; i < 1024; i += 256) {
        kl[i >> 6][i & 63] = kp[bh * 1024 + i];
        vl[i >> 6][i & 63] = vp[bh * 1024 + i];
    }
    alca[tid >> 4][tid & 15] = a_ca[bh * 256 + tid];
    if (tid < 16) iq[tid] = inv_qn[bh * 16 + tid];
    __syncthreads();
    int n = blockIdx.x * 256 + tid;

    {
        const short* vbase = qkvvb + (((size_t)(256 + bh * 16)) << 15) + n;
        float acc[16];
#pragma unroll
        for (int d = 0; d < 16; ++d) acc[d] = 0.f;
#pragma unroll
        for (int e = 0; e < 16; ++e) {
            float va = b2f(vbase[(size_t)e << 15]);
#pragma unroll
            for (int d = 0; d < 16; ++d) acc[d] += alca[d][e] * va;
        }
        short8 lo, hi;
#pragma unroll
        for (int j = 0; j < 8; ++j) { lo[j] = f2b(acc[j]); hi[j] = f2b(acc[j + 8]); }
        short* op = xcab + ((size_t)(b * NTOK + n)) * 64 + h * 16;
        *(short8*)&op[0] = lo;
        *(short8*)&op[8] = hi;
    }

    const short* qbase = qkvvb + (((size_t)(bh * 16)) << 15) + n;
    float qn_[16];
#pragma unroll
    for (int d = 0; d < 16; ++d) qn_[d] = b2f(qbase[(size_t)d << 15]) * iq[d];
    float t2 = temp2[h];
    float sc[64];
#pragma unroll
    for (int p = 0; p < 64; ++p) sc[p] = 0.f;
#pragma unroll
    for (int d = 0; d < 16; ++d) {
        float qv = qn_[d];
        const float4* kr = (const float4*)&kl[d][0];
#pragma unroll
        for (int p4 = 0; p4 < 16; ++p4) {
            float4 kv = kr[p4];
            sc[p4 * 4 + 0] += qv * kv.x; sc[p4 * 4 + 1] += qv * kv.y;
            sc[p4 * 4 + 2] += qv * kv.z; sc[p4 * 4 + 3] += qv * kv.w;
        }
    }
    float mx = -1e30f;
#pragma unroll
    for (int p = 0; p < 64; ++p) { sc[p] *= t2; mx = fmaxf(mx, sc[p]); }
    float s = 0.f;
#pragma unroll
    for (int p = 0; p < 64; ++p) { sc[p] = __expf(sc[p] - mx); s += sc[p]; }
    float inv = 1.f / s;
#pragma unroll
    for (int p = 0; p < 64; ++p) sc[p] *= inv;
    short* ob = xsab + (size_t)b * 2097152 + n;
#pragma unroll
    for (int d = 0; d < 16; ++d) {
        const float4* vr = (const float4*)&vl[d][0];
        float a0 = 0, a1 = 0, a2 = 0, a3 = 0;
#pragma unroll
        for (int p4 = 0; p4 < 16; ++p4) {
            float4 vv = vr[p4];
            a0 += sc[p4 * 4] * vv.x; a1 += sc[p4 * 4 + 1] * vv.y;
            a2 += sc[p4 * 4 + 2] * vv.z; a3 += sc[p4 * 4 + 3] * vv.w;
        }
        ob[(size_t)(d * 4 + h) << 15] = f2b((a0 + a1) + (a2 + a3));
    }
}

// ---------------- EPA epilogue (bf16 xsa/xca inputs) ----------------
__global__ __launch_bounds__(256) void k_epilogue(
    const float* __restrict__ x, const short* __restrict__ xsab,
    const short* __restrict__ xcab, const float* __restrict__ Wo1,
    const float* __restrict__ bo1, const float* __restrict__ Wo2,
    const float* __restrict__ bo2, const float* __restrict__ gamma,
    float* __restrict__ attn_skip, short* __restrict__ gA)
{
    __shared__ float W1[32][64];
    __shared__ float W2[32][64];
    int tid = threadIdx.x;
    for (int i = tid; i < 2048; i += 256) {
        W1[i >> 6][i & 63] = Wo1[i];
        W2[i >> 6][i & 63] = Wo2[i];
    }
    __syncthreads();
    int bid = blockIdx.x;
    int b = bid >> 9;
    int n0 = (bid & 511) << 6;
    int t = tid & 63, cg = tid >> 6;
    int n = n0 + t;
    const short* row = (cg < 2) ? xsab + (size_t)b * 2097152 + (size_t)n * 64
                                : xcab + ((size_t)(b * NTOK + n)) * 64;
    const float* Wb = (cg < 2) ? &W1[(cg & 1) * 16][0] : &W2[(cg & 1) * 16][0];
    const float* bias = (cg < 2) ? bo1 + (cg & 1) * 16 : bo2 + (cg & 1) * 16;
    float acc[16];
#pragma unroll
    for (int j = 0; j < 16; ++j) acc[j] = 0.f;
#pragma unroll
    for (int c8 = 0; c8 < 8; ++c8) {
        short8 rv8 = *(const short8*)&row[c8 * 8];
        float rv[8];
#pragma unroll
        for (int q = 0; q < 8; ++q) rv[q] = b2f(rv8[q]);
#pragma unroll
        for (int j = 0; j < 16; ++j) {
            const float* wr = &Wb[j * 64 + c8 * 8];
#pragma unroll
            for (int q = 0; q < 8; ++q) acc[j] += rv[q] * wr[q];
        }
    }
    float vals[16];
#pragma unroll
    for (int j = 0; j < 16; ++j) {
        int c = cg * 16 + j;
        size_t idx = (((size_t)(b * 64 + c)) << 15) + n;
        float v = x[idx] + gamma[c] * (acc[j] + bias[j]);
        attn_skip[idx] = v;
        vals[j] = v;
    }
    short8 lo, hi;
#pragma unroll
    for (int j = 0; j < 8; ++j) { lo[j] = f2b(vals[j]); hi[j] = f2b(vals[j + 8]); }
    short* gp = gA + ((size_t)(b * NTOK + n)) * 64 + cg * 16;
    *(short8*)&gp[0] = lo;
    *(short8*)&gp[8] = hi;
}

// ---------------- MFMA implicit-GEMM 3x3x3 conv (round-4 proven structure) ----------------
// Per-tap LDS double-buffered weights w/ register prefetch (coalesced), 1 barrier/tap.
// MODE 0: out = lrelu(bn1(conv))                     -> goutS NHWC bf16
// MODE 1: out2 = lrelu(bn2(conv)+skip); fused conv8: io = skip + conv8(out2) + b8
template <int MODE>
__global__ __launch_bounds__(256) void k_conv3m(
    const short* __restrict__ gin, const short* __restrict__ wb,
    const float* __restrict__ bnw, const float* __restrict__ bnb,
    const float* __restrict__ skip, short* __restrict__ goutS,
    const short* __restrict__ wb8, const float* __restrict__ b8,
    float* __restrict__ io)
{
    __shared__ __align__(16) short inl_s[24480];   // [3z][6y][34x][40 icpad]
    __shared__ __align__(16) short wl_s[5120];     // 2x [64 oc][40 icpad]; later w8 [64][80]
    __shared__ __align__(16) short a2_s[MODE ? 9216 : 16];
    int bx = blockIdx.x;
    int bb = bx >> 8;
    int z0 = (bx >> 3) & 31;
    int y0 = (bx & 7) * 4;
    int tid = threadIdx.x;
    int lane = tid & 63, wv = tid >> 6;
    int l15 = lane & 15, quad = lane >> 4;
    int wo = tid >> 2, wq = tid & 3;

    f32x4 acc[2][4];
#pragma unroll
    for (int s = 0; s < 2; ++s)
#pragma unroll
        for (int nt = 0; nt < 4; ++nt) acc[s][nt] = (f32x4){0.f, 0.f, 0.f, 0.f};

    int boff[4];
#pragma unroll
    for (int nt = 0; nt < 4; ++nt) boff[nt] = (nt * 16 + l15) * 40 + quad * 8;

    for (int chunk = 0; chunk < 2; ++chunk) {
        __syncthreads();
        for (int i = tid; i < 2448; i += 256) {
            int p = i >> 2, icq = i & 3;
            int xi = p % 34; int t2 = p / 34; int yi = t2 % 6; int zi = t2 / 6;
            int gz = z0 + zi - 1, gy = y0 + yi - 1, gx = xi - 1;
            short8 v = {0, 0, 0, 0, 0, 0, 0, 0};
            if ((unsigned)gz < 32u && (unsigned)gy < 32u && (unsigned)gx < 32u)
                v = *(const short8*)&gin[((size_t)(bb * NTOK + gz * 1024 + gy * 32 + gx)) * 64 + chunk * 32 + icq * 8];
            *(short8*)&inl_s[p * 40 + icq * 8] = v;
        }
        short8 wreg = *(const short8*)&wb[(size_t)wo * 64 + chunk * 32 + wq * 8];
        for (int tap = 0; tap < 27; ++tap) {
            *(short8*)&wl_s[(tap & 1) * 2560 + wo * 40 + wq * 8] = wreg;
            if (tap < 26)
                wreg = *(const short8*)&wb[(size_t)((tap + 1) * 64 + wo) * 64 + chunk * 32 + wq * 8];
            __syncthreads();
            int kz = tap / 9, ky = (tap / 3) % 3, kx = tap % 3;
            const short* wlb = &wl_s[(tap & 1) * 2560];
            short8 bf[4];
#pragma unroll
            for (int nt = 0; nt < 4; ++nt) bf[nt] = *(const short8*)&wlb[boff[nt]];
            int rowb = (kz * 6 + wv + ky) * 34;
#pragma unroll
            for (int s = 0; s < 2; ++s) {
                short8 af = *(const short8*)&inl_s[(rowb + s * 16 + l15 + kx) * 40 + quad * 8];
#pragma unroll
                for (int nt = 0; nt < 4; ++nt)
                    acc[s][nt] = __builtin_amdgcn_mfma_f32_16x16x32_bf16(af, bf[nt], acc[s][nt], 0, 0, 0);
            }
        }
    }
    __syncthreads();
    float rb = rsqrtf(1.f + 1e-5f);
    if (MODE == 0) {
        short* outS = inl_s;  // [128 pos][72 pad] bf16
#pragma unroll
        for (int nt = 0; nt < 4; ++nt) {
            int oc = nt * 16 + l15;
            float sc_ = bnw[oc] * rb, sh_ = bnb[oc];
#pragma unroll
            for (int s = 0; s < 2; ++s) {
                f32x4 v = acc[s][nt];
#pragma unroll
                for (int r = 0; r < 4; ++r) {
                    int pos = wv * 32 + s * 16 + quad * 4 + r;
                    float val = v[r] * sc_ + sh_;
                    val = val >= 0.f ? val : 0.01f * val;
                    outS[pos * 72 + oc] = f2b(val);
                }
            }
        }
        __syncthreads();
        for (int i = tid; i < 1024; i += 256) {
            int p = i >> 3, cq = i & 7;
            short8 v = *(const short8*)&outS[p * 72 + cq * 8];
            int y = p >> 5, x = p & 31;
            *(short8*)&goutS[((size_t)(bb * NTOK + z0 * 1024 + (y0 + y) * 32 + x)) * 64 + cq * 8] = v;
        }
    } else {
        float* outF = (float*)inl_s;  // [64 oc][132 pad pos] fp32
#pragma unroll
        for (int nt = 0; nt < 4; ++nt) {
            int oc = nt * 16 + l15;
#pragma unroll
            for (int s = 0; s < 2; ++s) {
                f32x4 v = acc[s][nt];
#pragma unroll
                for (int r = 0; r < 4; ++r) {
                    int pos = wv * 32 + s * 16 + quad * 4 + r;
                    outF[oc * 132 + pos] = v[r];
                }
            }
        }
        __syncthreads();
        f32x4 skr[8];
#pragma unroll
        for (int it = 0; it < 8; ++it) {
            int i = it * 256 + tid;
            int oc = i >> 5, xq = i & 31, pos0 = xq * 4;
            f32x4 c4 = *(const f32x4*)&outF[oc * 132 + pos0];
            int y = pos0 >> 5, xx = pos0 & 31;
            size_t g = (((size_t)(bb * 64 + oc)) << 15) + ((z0 * 32 + (y0 + y)) * 32 + xx);
            f32x4 sk = *(const f32x4*)&skip[g];
            skr[it] = sk;
            float sc_ = bnw[oc] * rb, sh_ = bnb[oc];
#pragma unroll
            for (int r = 0; r < 4; ++r) {
                float val = c4[r] * sc_ + sh_ + sk[r];
                val = val >= 0.f ? val : 0.01f * val;
                a2_s[(pos0 + r) * 72 + oc] = f2b(val);
            }
        }
        // stage w8 bf16 [64 out][80 pad]
        for (int i = tid; i < 512; i += 256) {
            int ocw = i >> 3, cq = i & 7;
            *(short8*)&wl_s[ocw * 80 + cq * 8] = *(const short8*)&wb8[ocw * 64 + cq * 8];
        }
        __syncthreads();
        f32x4 acc2[2][4];
#pragma unroll
        for (int s = 0; s < 2; ++s)
#pragma unroll
            for (int nt = 0; nt < 4; ++nt) acc2[s][nt] = (f32x4){0.f, 0.f, 0.f, 0.f};
#pragma unroll
        for (int ks = 0; ks < 2; ++ks) {
            short8 a8[2], b8f[4];
#pragma unroll
            for (int s = 0; s < 2; ++s)
                a8[s] = *(const short8*)&a2_s[(wv * 32 + s * 16 + l15) * 72 + quad * 8 + ks * 32];
#pragma unroll
            for (int nt = 0; nt < 4; ++nt)
                b8f[nt] = *(const short8*)&wl_s[(nt * 16 + l15) * 80 + quad * 8 + ks * 32];
#pragma unroll
            for (int s = 0; s < 2; ++s)
#pragma unroll
                for (int nt = 0; nt < 4; ++nt)
                    acc2[s][nt] = __builtin_amdgcn_mfma_f32_16x16x32_bf16(a8[s], b8f[nt], acc2[s][nt], 0, 0, 0);
        }
        __syncthreads();
#pragma unroll
        for (int nt = 0; nt < 4; ++nt) {
            int oc = nt * 16 + l15;
#pragma unroll
            for (int s = 0; s < 2; ++s) {
                f32x4 v = acc2[s][nt];
#pragma unroll
                for (int r = 0; r < 4; ++r) {
                    int pos = wv * 32 + s * 16 + quad * 4 + r;
                    outF[oc * 132 + pos] = v[r];
                }
            }
        }
        __syncthreads();
#pragma unroll
        for (int it = 0; it < 8; ++it) {
            int i = it * 256 + tid;
            int oc = i >> 5, xq = i & 31, pos0 = xq * 4;
            f32x4 cv = *(const f32x4*)&outF[oc * 132 + pos0];
            int y = pos0 >> 5, xx = pos0 & 31;
            size_t g = (((size_t)(bb * 64 + oc)) << 15) + ((z0 * 32 + (y0 + y)) * 32 + xx);
            float bias8 = b8[oc];
            f32x4 o;
#pragma unroll
            for (int r = 0; r < 4; ++r) o[r] = skr[it][r] + cv[r] + bias8;
            *(f32x4*)&io[g] = o;
        }
    }
}

extern "C" void kernel_launch(void* const* d_in, const int* in_sizes, int n_in,
                              void* d_out, int out_size, void* d_ws, size_t ws_size,
                              hipStream_t stream) {
    const float* x      = (const float*)d_in[0];
    const float* ln_w   = (const float*)d_in[1];
    const float* ln_b   = (const float*)d_in[2];
    const float* gamma  = (const float*)d_in[3];
    const float* temp1  = (const float*)d_in[4];
    const float* temp2  = (const float*)d_in[5];
    const float* W_qkvv = (const float*)d_in[6];
    const float* W_EF   = (const float*)d_in[7];
    const float* b_EF   = (const float*)d_in[8];
    const float* W_o1   = (const float*)d_in[9];
    const float* b_o1   = (const float*)d_in[10];
    const float* W_o2   = (const float*)d_in[11];
    const float* b_o2   = (const float*)d_in[12];
    const float* conv1w = (const float*)d_in[13];
    const float* conv2w = (const float*)d_in[14];
    const float* bn1_w  = (const float*)d_in[15];
    const float* bn1_b  = (const float*)d_in[16];
    const float* bn2_w  = (const float*)d_in[17];
    const float* bn2_b  = (const float*)d_in[18];
    const float* conv8w = (const float*)d_in[19];
    const float* conv8b = (const float*)d_in[20];

    // qkvvb = 512 rows x 32768 = 16,777,216 shorts (32 MB); all else after it.
    short* qkvvb = (short*)d_ws;                 // [0, 16777216) shorts
    float* kp    = (float*)(qkvvb + 16777216);   // 8192 floats
    float* vp    = kp + 8192;                    // 8192
    float* qd    = vp + 8192;                    // 2048
    float* qn_acc= qd + 2048;                    // 128
    float* kn_acc= qn_acc + 128;                 // 128
    float* a_ca  = kn_acc + 128;                 // 2048
    float* iqn   = a_ca + 2048;                  // 128
    float* ikn   = iqn + 128;                    // 128
    short* xcab  = (short*)(ikn + 128);          // 4194304 shorts
    short* xsab  = xcab + 4194304;               // 4194304
    short* gA    = xsab + 4194304;               // 4194304
    short* g1    = gA + 4194304;                 // 4194304
    short* wb1   = g1 + 4194304;                 // 110592
    short* wb2   = wb1 + 110592;                 // 110592
    short* wb8   = wb2 + 110592;                 // 4096
    short* wefb  = wb8 + 4096;                   // 2097152
    short* wqb   = wefb + 2097152;               // 16384

    float* attn_skip = (float*)d_out;

    hipLaunchKernelGGL(k_repack, dim3(9177), dim3(256), 0, stream,
                       conv1w, conv2w, conv8w, W_EF, W_qkvv, b_EF,
                       wb1, wb2, wb8, wefb, wqb, kp, vp, qd);
    hipLaunchKernelGGL(k_ln_qkvv, dim3(1024), dim3(256), 0, stream,
                       x, ln_w, ln_b, wqb, qkvvb);
    hipLaunchKernelGGL(k_pq, dim3(32, 8), dim3(256), 0, stream,
                       qkvvb, wefb, kp, vp, qd, qn_acc, kn_acc);
    hipLaunchKernelGGL(k_softmax_ca, dim3(1), dim3(256), 0, stream,
                       qd, qn_acc, kn_acc, temp1, a_ca, iqn, ikn);
    hipLaunchKernelGGL(k_attn, dim3(128, 8), dim3(256), 0, stream,
                       qkvvb, iqn, kp, vp, temp2, a_ca, xsab, xcab);
    hipLaunchKernelGGL(k_epilogue, dim3(1024), dim3(256), 0, stream,
                       x, xsab, xcab, W_o1, b_o1, W_o2, b_o2, gamma, attn_skip, gA);
    hipLaunchKernelGGL((k_conv3m<0>), dim3(512), dim3(256), 0, stream,
                       gA, wb1, bn1_w, bn1_b, (const float*)nullptr, g1,
                       (const short*)nullptr, (const float*)nullptr, (float*)nullptr);
    hipLaunchKernelGGL((k_conv3m<1>), dim3(512), dim3(256), 0, stream,
                       g1, wb2, bn2_w, bn2_b, attn_skip, (short*)nullptr,
                       wb8, conv8b, attn_skip);
}

// Round 10
// 229.546 us; speedup vs baseline: 1.3527x; 1.1178x over previous
//
#include <hip/hip_runtime.h>

#define NTOK 32768

typedef __attribute__((ext_vector_type(8))) short short8;
typedef __attribute__((ext_vector_type(4))) short short4_t;
typedef __attribute__((ext_vector_type(4))) float f32x4;

__device__ __forceinline__ short f2b(float f) {
    union { float f; unsigned u; } v; v.f = f;
    unsigned r = v.u + 0x7fffu + ((v.u >> 16) & 1u);
    return (short)(r >> 16);
}
__device__ __forceinline__ float b2f(short s) {
    union { float f; unsigned u; } v;
    v.u = ((unsigned)(unsigned short)s) << 16;
    return v.f;
}

// ------- setup: repack conv weights, bf16 conversions, init accumulators -------
__global__ void k_repack(const float* __restrict__ w1, const float* __restrict__ w2,
                         const float* __restrict__ w8, const float* __restrict__ wef,
                         const float* __restrict__ wq, const float* __restrict__ bEF,
                         short* __restrict__ wb1, short* __restrict__ wb2,
                         short* __restrict__ wb8, short* __restrict__ wefb,
                         short* __restrict__ wqb, float* __restrict__ kp,
                         float* __restrict__ vp, float* __restrict__ qd)
{
    int i = blockIdx.x * 256 + threadIdx.x;
    if (i >= 2349312) return;
    if (i >= 2347008) { qd[i - 2347008] = 0.f; return; }
    if (i >= 2338816) {
        int j = i - 2338816;
        float v = bEF[j & 63];
        kp[j] = v; vp[j] = v; return;
    }
    if (i >= 2322432) { int j = i - 2322432; wqb[j] = f2b(wq[j]); return; }
    if (i >= 225280)  { int j = i - 225280;  wefb[j] = f2b(wef[j]); return; }
    if (i >= 221184)  { int j = i - 221184;  wb8[j] = f2b(w8[j]); return; }
    int sel = i >= 110592;
    int j = sel ? i - 110592 : i;
    int tap = j >> 12;
    int r = j & 4095;
    int oc = r >> 6, ic = r & 63;
    const float* w = sel ? w2 : w1;
    short* o = sel ? wb2 : wb1;
    o[j] = f2b(w[(oc * 64 + ic) * 27 + tap]);
}

// ---------------- fused LayerNorm + QKVV GEMM (MFMA), bf16 W ----------------
// qkvvb layout: bf16 [isel(4)][b(2)][h(4)][d(16)][N]  (512 rows x 32768 = 32 MB)
__global__ __launch_bounds__(256) void k_ln_qkvv(
    const float* __restrict__ x, const float* __restrict__ lnw,
    const float* __restrict__ lnb, const short* __restrict__ wqb,
    short* __restrict__ qkvvb)
{
    __shared__ __align__(16) short Wl[256 * 72];
    __shared__ __align__(16) short tr[256 * 72];
    __shared__ float red1[4][64], red2[4][64];
    __shared__ float mu_s[64], rs_s[64];
    short* al = tr;                                 // bf16 [64 t][72]

    int bid = blockIdx.x;
    int b = bid >> 9;
    int n0 = (bid & 511) << 6;
    int tid = threadIdx.x;

    for (int i = tid; i < 2048; i += 256) {
        int out = i >> 3, q8 = (i & 7) * 8;
        *(short8*)&Wl[out * 72 + q8] = *(const short8*)&wqb[out * 64 + q8];
    }

    int t = tid & 63, cq = tid >> 6;
    float xr[16];
    float s1 = 0.f, s2 = 0.f;
    const float* xb = x + (((size_t)(b * 64 + cq * 16)) << 15) + n0 + t;
#pragma unroll
    for (int j = 0; j < 16; ++j) {
        float v = xb[(size_t)j << 15];
        xr[j] = v; s1 += v; s2 += v * v;
    }
    red1[cq][t] = s1; red2[cq][t] = s2;
    __syncthreads();
    if (tid < 64) {
        float a = red1[0][tid] + red1[1][tid] + red1[2][tid] + red1[3][tid];
        float q = red2[0][tid] + red2[1][tid] + red2[2][tid] + red2[3][tid];
        float mu = a * (1.f / 64.f);
        float var = q * (1.f / 64.f) - mu * mu;
        mu_s[tid] = mu;
        rs_s[tid] = rsqrtf(var + 1e-5f);
    }
    __syncthreads();
    {
        float mu = mu_s[t], rs = rs_s[t];
        short8 p0, p1;
#pragma unroll
        for (int j = 0; j < 8; ++j) {
            int c = cq * 16 + j;
            p0[j] = f2b((xr[j] - mu) * rs * lnw[c] + lnb[c]);
        }
#pragma unroll
        for (int j = 0; j < 8; ++j) {
            int c = cq * 16 + 8 + j;
            p1[j] = f2b((xr[8 + j] - mu) * rs * lnw[c] + lnb[c]);
        }
        *(short8*)&al[t * 72 + cq * 16] = p0;
        *(short8*)&al[t * 72 + cq * 16 + 8] = p1;
    }
    __syncthreads();

    int w = tid >> 6, lane = tid & 63, l15 = lane & 15, quad = lane >> 4;
    f32x4 acc[4][4];
#pragma unroll
    for (int mt = 0; mt < 4; ++mt)
#pragma unroll
        for (int nt = 0; nt < 4; ++nt) acc[mt][nt] = (f32x4){0.f, 0.f, 0.f, 0.f};
#pragma unroll
    for (int ks = 0; ks < 2; ++ks) {
        short8 af[4], bf[4];
#pragma unroll
        for (int mt = 0; mt < 4; ++mt)
            af[mt] = *(const short8*)&al[(mt * 16 + l15) * 72 + quad * 8 + ks * 32];
#pragma unroll
        for (int nt = 0; nt < 4; ++nt)
            bf[nt] = *(const short8*)&Wl[(w * 64 + nt * 16 + l15) * 72 + quad * 8 + ks * 32];
#pragma unroll
        for (int mt = 0; mt < 4; ++mt)
#pragma unroll
            for (int nt = 0; nt < 4; ++nt)
                acc[mt][nt] = __builtin_amdgcn_mfma_f32_16x16x32_bf16(af[mt], bf[nt], acc[mt][nt], 0, 0, 0);
    }
    __syncthreads();

#pragma unroll
    for (int mt = 0; mt < 4; ++mt)
#pragma unroll
        for (int nt = 0; nt < 4; ++nt) {
            int out = w * 64 + nt * 16 + l15;
            short4_t sv;
#pragma unroll
            for (int r = 0; r < 4; ++r) sv[r] = f2b(acc[mt][nt][r]);
            *(short4_t*)&tr[out * 72 + mt * 16 + quad * 4] = sv;
        }
    __syncthreads();
    for (int i = tid; i < 2048; i += 256) {
        int o = i >> 3, tq = (i & 7) * 8;
        short8 v = *(const short8*)&tr[o * 72 + tq];
        int isel = o >> 6, h = (o >> 4) & 3, d = o & 15;
        *(short8*)&qkvvb[((size_t)(((isel * 2 + b) * 4 + h) * 16 + d) << 15) + n0 + tq] = v;
    }
}

// ------- merged MFMA: k/v projections + q.k logits + L2-norm accumulators -------
__global__ __launch_bounds__(256) void k_pq(
    const short* __restrict__ qkvvb, const short* __restrict__ wefb,
    float* __restrict__ kp, float* __restrict__ vp, float* __restrict__ qd,
    float* __restrict__ qn_acc, float* __restrict__ kn_acc)
{
    __shared__ float redb[3][64][38];
    int kc = blockIdx.x, bh = blockIdx.y;
    int tid = threadIdx.x;
    int w = tid >> 6, lane = tid & 63, l15 = lane & 15, quad = lane >> 4;
    size_t qrow = ((size_t)(bh * 16 + l15)) << 15;
    size_t krow = ((size_t)(128 + bh * 16 + l15)) << 15;
    size_t vrow = ((size_t)(384 + bh * 16 + l15)) << 15;
    int nbase = kc * 1024 + w * 256 + quad * 8;
    f32x4 acck[4], accv[4], accqd, accqq, acckk;
#pragma unroll
    for (int nt = 0; nt < 4; ++nt) {
        acck[nt] = (f32x4){0.f, 0.f, 0.f, 0.f};
        accv[nt] = (f32x4){0.f, 0.f, 0.f, 0.f};
    }
    accqd = (f32x4){0.f, 0.f, 0.f, 0.f};
    accqq = (f32x4){0.f, 0.f, 0.f, 0.f};
    acckk = (f32x4){0.f, 0.f, 0.f, 0.f};
#pragma unroll
    for (int ks = 0; ks < 8; ++ks) {
        int n = nbase + ks * 32;
        short8 qf = *(const short8*)&qkvvb[qrow + n];
        short8 kf = *(const short8*)&qkvvb[krow + n];
        short8 vf = *(const short8*)&qkvvb[vrow + n];
        accqd = __builtin_amdgcn_mfma_f32_16x16x32_bf16(qf, kf, accqd, 0, 0, 0);
        accqq = __builtin_amdgcn_mfma_f32_16x16x32_bf16(qf, qf, accqq, 0, 0, 0);
        acckk = __builtin_amdgcn_mfma_f32_16x16x32_bf16(kf, kf, acckk, 0, 0, 0);
#pragma unroll
        for (int nt = 0; nt < 4; ++nt) {
            short8 wf = *(const short8*)&wefb[(((size_t)(nt * 16 + l15)) << 15) + n];
            acck[nt] = __builtin_amdgcn_mfma_f32_16x16x32_bf16(kf, wf, acck[nt], 0, 0, 0);
            accv[nt] = __builtin_amdgcn_mfma_f32_16x16x32_bf16(vf, wf, accv[nt], 0, 0, 0);
        }
    }
    int diag = (quad == (l15 >> 2));
    float qqv = diag ? accqq[l15 & 3] : 0.f;
    float kkv = diag ? acckk[l15 & 3] : 0.f;
    if (w > 0) {
        float* p = &redb[w - 1][lane][0];
#pragma unroll
        for (int nt = 0; nt < 4; ++nt)
#pragma unroll
            for (int r = 0; r < 4; ++r) { p[nt * 4 + r] = acck[nt][r]; p[16 + nt * 4 + r] = accv[nt][r]; }
#pragma unroll
        for (int r = 0; r < 4; ++r) p[32 + r] = accqd[r];
        p[36] = qqv; p[37] = kkv;
    }
    __syncthreads();
    if (w == 0) {
#pragma unroll
        for (int wv = 0; wv < 3; ++wv) {
            const float* p = &redb[wv][lane][0];
#pragma unroll
            for (int nt = 0; nt < 4; ++nt)
#pragma unroll
                for (int r = 0; r < 4; ++r) { acck[nt][r] += p[nt * 4 + r]; accv[nt][r] += p[16 + nt * 4 + r]; }
#pragma unroll
            for (int r = 0; r < 4; ++r) accqd[r] += p[32 + r];
            qqv += p[36]; kkv += p[37];
        }
        int d = quad * 4;
#pragma unroll
        for (int nt = 0; nt < 4; ++nt)
#pragma unroll
            for (int r = 0; r < 4; ++r) {
                int idx = (bh * 16 + d + r) * 64 + nt * 16 + l15;
                atomicAdd(&kp[idx], acck[nt][r]);
                atomicAdd(&vp[idx], accv[nt][r]);
            }
#pragma unroll
        for (int r = 0; r < 4; ++r)
            atomicAdd(&qd[bh * 256 + (d + r) * 16 + l15], accqd[r]);
        if (diag) {
            atomicAdd(&qn_acc[bh * 16 + l15], qqv);
            atomicAdd(&kn_acc[bh * 16 + l15], kkv);
        }
    }
}

// ---------------- norm finalize + channel-attention softmax ----------------
__global__ void k_softmax_ca(const float* __restrict__ qd,
    const float* __restrict__ qn_acc, const float* __restrict__ kn_acc,
    const float* __restrict__ temp1, float* __restrict__ attn,
    float* __restrict__ iqn, float* __restrict__ ikn)
{
    __shared__ float iqs[128], iks[128];
    int tid = threadIdx.x;
    if (tid < 128) {
        float v = 1.f / fmaxf(sqrtf(qn_acc[tid]), 1e-12f);
        iqs[tid] = v; iqn[tid] = v;
    } else {
        int j = tid - 128;
        float v = 1.f / fmaxf(sqrtf(kn_acc[j]), 1e-12f);
        iks[j] = v; ikn[j] = v;
    }
    __syncthreads();
    int r = tid;
    if (r >= 128) return;
    int bh = r >> 4;
    int h = bh & 3;
    float iq = iqs[r];
    float t1 = temp1[h];
    float sc[16];
    float mx = -1e30f;
#pragma unroll
    for (int e = 0; e < 16; ++e) {
        float v = qd[r * 16 + e] * iq * iks[bh * 16 + e] * t1;
        sc[e] = v; mx = fmaxf(mx, v);
    }
    float s = 0.f;
#pragma unroll
    for (int e = 0; e < 16; ++e) { sc[e] = __expf(sc[e] - mx); s += sc[e]; }
    float inv = 1.f / s;
#pragma unroll
    for (int e = 0; e < 16; ++e) attn[r * 16 + e] = sc[e] * inv;
}

// ---------------- fused x_ca + spatial attention; bf16 outputs ----------------
__global__ __launch_bounds__(256) void k_attn(
    const short* __restrict__ qkvvb, const float* __restrict__ inv_qn,
    const float* __restrict__ kp, const float* __restrict__ vp,
    const float* __restrict__ temp2, const float* __restrict__ a_ca,
    short* __restrict__ xsab, short* __restrict__ xcab)
{
    __shared__ float kl[16][64];
    __shared__ float vl[16][64];
    __shared__ float alca[16][16];
    __shared__ float iq[16];
    int bh = blockIdx.y; int b = bh >> 2, h = bh & 3;
    int tid = threadIdx.x;
    for (int i = tid; i < 1024; i += 256) {
        kl[i >> 6][i & 63] = kp[bh * 1024 + i];
        vl[i >> 6][i & 63] = vp[bh * 1024 + i];
    }
    alca[tid >> 4][tid & 15] = a_ca[bh * 256 + tid];
    if (tid < 16) iq[tid] = inv_qn[bh * 16 + tid];
    __syncthreads();
    int n = blockIdx.x * 256 + tid;

    {
        const short* vbase = qkvvb + (((size_t)(256 + bh * 16)) << 15) + n;
        float acc[16];
#pragma unroll
        for (int d = 0; d < 16; ++d) acc[d] = 0.f;
#pragma unroll
        for (int e = 0; e < 16; ++e) {
            float va = b2f(vbase[(size_t)e << 15]);
#pragma unroll
            for (int d = 0; d < 16; ++d) acc[d] += alca[d][e] * va;
        }
        short8 lo, hi;
#pragma unroll
        for (int j = 0; j < 8; ++j) { lo[j] = f2b(acc[j]); hi[j] = f2b(acc[j + 8]); }
        short* op = xcab + ((size_t)(b * NTOK + n)) * 64 + h * 16;
        *(short8*)&op[0] = lo;
        *(short8*)&op[8] = hi;
    }

    const short* qbase = qkvvb + (((size_t)(bh * 16)) << 15) + n;
    float qn_[16];
#pragma unroll
    for (int d = 0; d < 16; ++d) qn_[d] = b2f(qbase[(size_t)d << 15]) * iq[d];
    float t2 = temp2[h];
    float sc[64];
#pragma unroll
    for (int p = 0; p < 64; ++p) sc[p] = 0.f;
#pragma unroll
    for (int d = 0; d < 16; ++d) {
        float qv = qn_[d];
        const float4* kr = (const float4*)&kl[d][0];
#pragma unroll
        for (int p4 = 0; p4 < 16; ++p4) {
            float4 kv = kr[p4];
            sc[p4 * 4 + 0] += qv * kv.x; sc[p4 * 4 + 1] += qv * kv.y;
            sc[p4 * 4 + 2] += qv * kv.z; sc[p4 * 4 + 3] += qv * kv.w;
        }
    }
    float mx = -1e30f;
#pragma unroll
    for (int p = 0; p < 64; ++p) { sc[p] *= t2; mx = fmaxf(mx, sc[p]); }
    float s = 0.f;
#pragma unroll
    for (int p = 0; p < 64; ++p) { sc[p] = __expf(sc[p] - mx); s += sc[p]; }
    float inv = 1.f / s;
#pragma unroll
    for (int p = 0; p < 64; ++p) sc[p] *= inv;
    short* ob = xsab + (size_t)b * 2097152 + n;
#pragma unroll
    for (int d = 0; d < 16; ++d) {
        const float4* vr = (const float4*)&vl[d][0];
        float a0 = 0, a1 = 0, a2 = 0, a3 = 0;
#pragma unroll
        for (int p4 = 0; p4 < 16; ++p4) {
            float4 vv = vr[p4];
            a0 += sc[p4 * 4] * vv.x; a1 += sc[p4 * 4 + 1] * vv.y;
            a2 += sc[p4 * 4 + 2] * vv.z; a3 += sc[p4 * 4 + 3] * vv.w;
        }
        ob[(size_t)(d * 4 + h) << 15] = f2b((a0 + a1) + (a2 + a3));
    }
}

// ---------------- EPA epilogue (MFMA): proj + gamma + residual ----------------
// Per block: 256 output-tokens. acc C-layout: col=outc, row=token.
__global__ __launch_bounds__(256) void k_epilogue(
    const float* __restrict__ x, const short* __restrict__ xsab,
    const short* __restrict__ xcab, const float* __restrict__ Wo1,
    const float* __restrict__ bo1, const float* __restrict__ Wo2,
    const float* __restrict__ bo2, const float* __restrict__ gamma,
    float* __restrict__ attn_skip, short* __restrict__ gA)
{
    __shared__ __align__(16) short Wl[64 * 72];    // rows 0-31: Wo1, 32-63: Wo2 (bf16)
    __shared__ __align__(16) short trS[256 * 72];  // bf16 [256 tok][72] for gA transpose
    int tid = threadIdx.x;
    int bidx = blockIdx.x;
    int b = bidx >> 7;
    int n0 = (bidx & 127) << 8;                    // 256 tokens per block
    for (int i = tid; i < 4096; i += 256) {
        int row = i >> 6, c = i & 63;
        float wv = (row < 32) ? Wo1[row * 64 + c] : Wo2[(row - 32) * 64 + c];
        Wl[row * 72 + c] = f2b(wv);
    }
    __syncthreads();

    int w = tid >> 6, lane = tid & 63, l15 = lane & 15, quad = lane >> 4;
    int tw = n0 + w * 64;
    const short* sa_base = xsab + (size_t)b * 2097152;
    const short* ca_base = xcab + (size_t)b * 2097152;

    f32x4 acc_sa[4][2], acc_ca[4][2];
#pragma unroll
    for (int mt = 0; mt < 4; ++mt)
#pragma unroll
        for (int nt = 0; nt < 2; ++nt) {
            acc_sa[mt][nt] = (f32x4){0.f, 0.f, 0.f, 0.f};
            acc_ca[mt][nt] = (f32x4){0.f, 0.f, 0.f, 0.f};
        }
#pragma unroll
    for (int ks = 0; ks < 2; ++ks) {
        int ko = quad * 8 + ks * 32;
        short8 b1[2], b2[2];
#pragma unroll
        for (int nt = 0; nt < 2; ++nt) {
            b1[nt] = *(const short8*)&Wl[(nt * 16 + l15) * 72 + ko];
            b2[nt] = *(const short8*)&Wl[(32 + nt * 16 + l15) * 72 + ko];
        }
#pragma unroll
        for (int mt = 0; mt < 4; ++mt) {
            int trow = tw + mt * 16 + l15;
            short8 a1 = *(const short8*)&sa_base[(size_t)trow * 64 + ko];
            short8 a2 = *(const short8*)&ca_base[(size_t)trow * 64 + ko];
#pragma unroll
            for (int nt = 0; nt < 2; ++nt) {
                acc_sa[mt][nt] = __builtin_amdgcn_mfma_f32_16x16x32_bf16(a1, b1[nt], acc_sa[mt][nt], 0, 0, 0);
                acc_ca[mt][nt] = __builtin_amdgcn_mfma_f32_16x16x32_bf16(a2, b2[nt], acc_ca[mt][nt], 0, 0, 0);
            }
        }
    }

    // fused residual: v = x + gamma*(acc + bias); write attn_skip (f32x4/lane);
    // stash bf16 into trS row=token (one scalar store per token — C rows differ!)
#pragma unroll
    for (int half = 0; half < 2; ++half) {   // 0: sa -> c in [0,32), 1: ca -> c in [32,64)
#pragma unroll
        for (int nt = 0; nt < 2; ++nt) {
            int c = half * 32 + nt * 16 + l15;
            float g = gamma[c];
            float bias = half ? bo2[c - 32] : bo1[c];
#pragma unroll
            for (int mt = 0; mt < 4; ++mt) {
                f32x4 a = half ? acc_ca[mt][nt] : acc_sa[mt][nt];
                int tbase = tw + mt * 16 + quad * 4;
                size_t gidx = (((size_t)(b * 64 + c)) << 15) + tbase;
                f32x4 xv = *(const f32x4*)&x[gidx];
                f32x4 o;
#pragma unroll
                for (int r = 0; r < 4; ++r) {
                    float v = xv[r] + g * (a[r] + bias);
                    o[r] = v;
                    trS[(w * 64 + mt * 16 + quad * 4 + r) * 72 + c] = f2b(v);
                }
                *(f32x4*)&attn_skip[gidx] = o;
            }
        }
    }
    __syncthreads();
    // coalesced NHWC gA write
    for (int i = tid; i < 2048; i += 256) {
        int tok = i >> 3, cq = (i & 7) * 8;
        short8 v = *(const short8*)&trS[tok * 72 + cq];
        *(short8*)&gA[((size_t)(b * NTOK + n0 + tok)) * 64 + cq] = v;
    }
}

// ---------------- MFMA implicit-GEMM 3x3x3 conv (round-4 proven structure) ----------------
template <int MODE>
__global__ __launch_bounds__(256) void k_conv3m(
    const short* __restrict__ gin, const short* __restrict__ wb,
    const float* __restrict__ bnw, const float* __restrict__ bnb,
    const float* __restrict__ skip, short* __restrict__ goutS,
    const short* __restrict__ wb8, const float* __restrict__ b8,
    float* __restrict__ io)
{
    __shared__ __align__(16) short inl_s[24480];   // [3z][6y][34x][40 icpad]
    __shared__ __align__(16) short wl_s[5120];     // 2x [64 oc][40 icpad]; later w8 [64][80]
    __shared__ __align__(16) short a2_s[MODE ? 9216 : 16];
    int bx = blockIdx.x;
    int bb = bx >> 8;
    int z0 = (bx >> 3) & 31;
    int y0 = (bx & 7) * 4;
    int tid = threadIdx.x;
    int lane = tid & 63, wv = tid >> 6;
    int l15 = lane & 15, quad = lane >> 4;
    int wo = tid >> 2, wq = tid & 3;

    f32x4 acc[2][4];
#pragma unroll
    for (int s = 0; s < 2; ++s)
#pragma unroll
        for (int nt = 0; nt < 4; ++nt) acc[s][nt] = (f32x4){0.f, 0.f, 0.f, 0.f};

    int boff[4];
#pragma unroll
    for (int nt = 0; nt < 4; ++nt) boff[nt] = (nt * 16 + l15) * 40 + quad * 8;

    for (int chunk = 0; chunk < 2; ++chunk) {
        __syncthreads();
        for (int i = tid; i < 2448; i += 256) {
            int p = i >> 2, icq = i & 3;
            int xi = p % 34; int t2 = p / 34; int yi = t2 % 6; int zi = t2 / 6;
            int gz = z0 + zi - 1, gy = y0 + yi - 1, gx = xi - 1;
            short8 v = {0, 0, 0, 0, 0, 0, 0, 0};
            if ((unsigned)gz < 32u && (unsigned)gy < 32u && (unsigned)gx < 32u)
                v = *(const short8*)&gin[((size_t)(bb * NTOK + gz * 1024 + gy * 32 + gx)) * 64 + chunk * 32 + icq * 8];
            *(short8*)&inl_s[p * 40 + icq * 8] = v;
        }
        short8 wreg = *(const short8*)&wb[(size_t)wo * 64 + chunk * 32 + wq * 8];
        for (int tap = 0; tap < 27; ++tap) {
            *(short8*)&wl_s[(tap & 1) * 2560 + wo * 40 + wq * 8] = wreg;
            if (tap < 26)
                wreg = *(const short8*)&wb[(size_t)((tap + 1) * 64 + wo) * 64 + chunk * 32 + wq * 8];
            __syncthreads();
            int kz = tap / 9, ky = (tap / 3) % 3, kx = tap % 3;
            const short* wlb = &wl_s[(tap & 1) * 2560];
            short8 bf[4];
#pragma unroll
            for (int nt = 0; nt < 4; ++nt) bf[nt] = *(const short8*)&wlb[boff[nt]];
            int rowb = (kz * 6 + wv + ky) * 34;
#pragma unroll
            for (int s = 0; s < 2; ++s) {
                short8 af = *(const short8*)&inl_s[(rowb + s * 16 + l15 + kx) * 40 + quad * 8];
#pragma unroll
                for (int nt = 0; nt < 4; ++nt)
                    acc[s][nt] = __builtin_amdgcn_mfma_f32_16x16x32_bf16(af, bf[nt], acc[s][nt], 0, 0, 0);
            }
        }
    }
    __syncthreads();
    float rb = rsqrtf(1.f + 1e-5f);
    if (MODE == 0) {
        short* outS = inl_s;  // [128 pos][72 pad] bf16
#pragma unroll
        for (int nt = 0; nt < 4; ++nt) {
            int oc = nt * 16 + l15;
            float sc_ = bnw[oc] * rb, sh_ = bnb[oc];
#pragma unroll
            for (int s = 0; s < 2; ++s) {
                f32x4 v = acc[s][nt];
#pragma unroll
                for (int r = 0; r < 4; ++r) {
                    int pos = wv * 32 + s * 16 + quad * 4 + r;
                    float val = v[r] * sc_ + sh_;
                    val = val >= 0.f ? val : 0.01f * val;
                    outS[pos * 72 + oc] = f2b(val);
                }
            }
        }
        __syncthreads();
        for (int i = tid; i < 1024; i += 256) {
            int p = i >> 3, cq = i & 7;
            short8 v = *(const short8*)&outS[p * 72 + cq * 8];
            int y = p >> 5, x = p & 31;
            *(short8*)&goutS[((size_t)(bb * NTOK + z0 * 1024 + (y0 + y) * 32 + x)) * 64 + cq * 8] = v;
        }
    } else {
        float* outF = (float*)inl_s;  // [64 oc][132 pad pos] fp32
#pragma unroll
        for (int nt = 0; nt < 4; ++nt) {
            int oc = nt * 16 + l15;
#pragma unroll
            for (int s = 0; s < 2; ++s) {
                f32x4 v = acc[s][nt];
#pragma unroll
                for (int r = 0; r < 4; ++r) {
                    int pos = wv * 32 + s * 16 + quad * 4 + r;
                    outF[oc * 132 + pos] = v[r];
                }
            }
        }
        __syncthreads();
        f32x4 skr[8];
#pragma unroll
        for (int it = 0; it < 8; ++it) {
            int i = it * 256 + tid;
            int oc = i >> 5, xq = i & 31, pos0 = xq * 4;
            f32x4 c4 = *(const f32x4*)&outF[oc * 132 + pos0];
            int y = pos0 >> 5, xx = pos0 & 31;
            size_t g = (((size_t)(bb * 64 + oc)) << 15) + ((z0 * 32 + (y0 + y)) * 32 + xx);
            f32x4 sk = *(const f32x4*)&skip[g];
            skr[it] = sk;
            float sc_ = bnw[oc] * rb, sh_ = bnb[oc];
#pragma unroll
            for (int r = 0; r < 4; ++r) {
                float val = c4[r] * sc_ + sh_ + sk[r];
                val = val >= 0.f ? val : 0.01f * val;
                a2_s[(pos0 + r) * 72 + oc] = f2b(val);
            }
        }
        // stage w8 bf16 [64 out][80 pad]
        for (int i = tid; i < 512; i += 256) {
            int ocw = i >> 3, cq = i & 7;
            *(short8*)&wl_s[ocw * 80 + cq * 8] = *(const short8*)&wb8[ocw * 64 + cq * 8];
        }
        __syncthreads();
        f32x4 acc2[2][4];
#pragma unroll
        for (int s = 0; s < 2; ++s)
#pragma unroll
            for (int nt = 0; nt < 4; ++nt) acc2[s][nt] = (f32x4){0.f, 0.f, 0.f, 0.f};
#pragma unroll
        for (int ks = 0; ks < 2; ++ks) {
            short8 a8[2], b8f[4];
#pragma unroll
            for (int s = 0; s < 2; ++s)
                a8[s] = *(const short8*)&a2_s[(wv * 32 + s * 16 + l15) * 72 + quad * 8 + ks * 32];
#pragma unroll
            for (int nt = 0; nt < 4; ++nt)
                b8f[nt] = *(const short8*)&wl_s[(nt * 16 + l15) * 80 + quad * 8 + ks * 32];
#pragma unroll
            for (int s = 0; s < 2; ++s)
#pragma unroll
                for (int nt = 0; nt < 4; ++nt)
                    acc2[s][nt] = __builtin_amdgcn_mfma_f32_16x16x32_bf16(a8[s], b8f[nt], acc2[s][nt], 0, 0, 0);
        }
        __syncthreads();
#pragma unroll
        for (int nt = 0; nt < 4; ++nt) {
            int oc = nt * 16 + l15;
#pragma unroll
            for (int s = 0; s < 2; ++s) {
                f32x4 v = acc2[s][nt];
#pragma unroll
                for (int r = 0; r < 4; ++r) {
                    int pos = wv * 32 + s * 16 + quad * 4 + r;
                    outF[oc * 132 + pos] = v[r];
                }
            }
        }
        __syncthreads();
#pragma unroll
        for (int it = 0; it < 8; ++it) {
            int i = it * 256 + tid;
            int oc = i >> 5, xq = i & 31, pos0 = xq * 4;
            f32x4 cv = *(const f32x4*)&outF[oc * 132 + pos0];
            int y = pos0 >> 5, xx = pos0 & 31;
            size_t g = (((size_t)(bb * 64 + oc)) << 15) + ((z0 * 32 + (y0 + y)) * 32 + xx);
            float bias8 = b8[oc];
            f32x4 o;
#pragma unroll
            for (int r = 0; r < 4; ++r) o[r] = skr[it][r] + cv[r] + bias8;
            *(f32x4*)&io[g] = o;
        }
    }
}

extern "C" void kernel_launch(void* const* d_in, const int* in_sizes, int n_in,
                              void* d_out, int out_size, void* d_ws, size_t ws_size,
                              hipStream_t stream) {
    const float* x      = (const float*)d_in[0];
    const float* ln_w   = (const float*)d_in[1];
    const float* ln_b   = (const float*)d_in[2];
    const float* gamma  = (const float*)d_in[3];
    const float* temp1  = (const float*)d_in[4];
    const float* temp2  = (const float*)d_in[5];
    const float* W_qkvv = (const float*)d_in[6];
    const float* W_EF   = (const float*)d_in[7];
    const float* b_EF   = (const float*)d_in[8];
    const float* W_o1   = (const float*)d_in[9];
    const float* b_o1   = (const float*)d_in[10];
    const float* W_o2   = (const float*)d_in[11];
    const float* b_o2   = (const float*)d_in[12];
    const float* conv1w = (const float*)d_in[13];
    const float* conv2w = (const float*)d_in[14];
    const float* bn1_w  = (const float*)d_in[15];
    const float* bn1_b  = (const float*)d_in[16];
    const float* bn2_w  = (const float*)d_in[17];
    const float* bn2_b  = (const float*)d_in[18];
    const float* conv8w = (const float*)d_in[19];
    const float* conv8b = (const float*)d_in[20];

    // qkvvb = 512 rows x 32768 = 16,777,216 shorts (32 MB); all else after it.
    short* qkvvb = (short*)d_ws;                 // [0, 16777216) shorts
    float* kp    = (float*)(qkvvb + 16777216);   // 8192 floats
    float* vp    = kp + 8192;                    // 8192
    float* qd    = vp + 8192;                    // 2048
    float* qn_acc= qd + 2048;                    // 128
    float* kn_acc= qn_acc + 128;                 // 128
    float* a_ca  = kn_acc + 128;                 // 2048
    float* iqn   = a_ca + 2048;                  // 128
    float* ikn   = iqn + 128;                    // 128
    short* xcab  = (short*)(ikn + 128);          // 4194304 shorts
    short* xsab  = xcab + 4194304;               // 4194304
    short* gA    = xsab + 4194304;               // 4194304
    short* g1    = gA + 4194304;                 // 4194304
    short* wb1   = g1 + 4194304;                 // 110592
    short* wb2   = wb1 + 110592;                 // 110592
    short* wb8   = wb2 + 110592;                 // 4096
    short* wefb  = wb8 + 4096;                   // 2097152
    short* wqb   = wefb + 2097152;               // 16384

    float* attn_skip = (float*)d_out;

    hipLaunchKernelGGL(k_repack, dim3(9177), dim3(256), 0, stream,
                       conv1w, conv2w, conv8w, W_EF, W_qkvv, b_EF,
                       wb1, wb2, wb8, wefb, wqb, kp, vp, qd);
    hipLaunchKernelGGL(k_ln_qkvv, dim3(1024), dim3(256), 0, stream,
                       x, ln_w, ln_b, wqb, qkvvb);
    hipLaunchKernelGGL(k_pq, dim3(32, 8), dim3(256), 0, stream,
                       qkvvb, wefb, kp, vp, qd, qn_acc, kn_acc);
    hipLaunchKernelGGL(k_softmax_ca, dim3(1), dim3(256), 0, stream,
                       qd, qn_acc, kn_acc, temp1, a_ca, iqn, ikn);
    hipLaunchKernelGGL(k_attn, dim3(128, 8), dim3(256), 0, stream,
                       qkvvb, iqn, kp, vp, temp2, a_ca, xsab, xcab);
    hipLaunchKernelGGL(k_epilogue, dim3(256), dim3(256), 0, stream,
                       x, xsab, xcab, W_o1, b_o1, W_o2, b_o2, gamma, attn_skip, gA);
    hipLaunchKernelGGL((k_conv3m<0>), dim3(512), dim3(256), 0, stream,
                       gA, wb1, bn1_w, bn1_b, (const float*)nullptr, g1,
                       (const short*)nullptr, (const float*)nullptr, (float*)nullptr);
    hipLaunchKernelGGL((k_conv3m<1>), dim3(512), dim3(256), 0, stream,
                       g1, wb2, bn2_w, bn2_b, attn_skip, (short*)nullptr,
                       wb8, conv8b, attn_skip);
}